// Round 4
// baseline (627.545 us; speedup 1.0000x reference)
//
#include <hip/hip_runtime.h>
#include <cstdint>
#include <cstddef>

// Problem constants
#define OBS_DIMM 128
#define PROJJ    64
#define HIDD     256
#define LATT     24
#define BBATCH   1024
#define TTIME    256
#define NGATE    768   // 3*HID
#define MBLK     16    // batches per block
#define CHUNK    64    // timesteps per block
#define NGROUP   64
#define NCHUNK   4
#define HSTR     264   // h/mish row stride (ushorts): 256 + 8 pad (16B-aligned, bank-skewed)

using bf16x8 = __attribute__((ext_vector_type(8))) short;   // 8 bf16 in 4 VGPRs
using f32x4  = __attribute__((ext_vector_type(4))) float;

static __device__ __forceinline__ unsigned short f2bf(float f) {
    unsigned u = __builtin_bit_cast(unsigned, f);
    u += 0x7fffu + ((u >> 16) & 1u);          // RNE
    return (unsigned short)(u >> 16);
}
static __device__ __forceinline__ float bf2f(unsigned short h) {
    return __builtin_bit_cast(float, ((unsigned)h) << 16);
}
// Packed RNE f32->bf16 pair: 1 instr replaces ~10 ops of manual bit-twiddle.
// v_cvt_pk_bf16_f32: D[15:0]=bf16(S0), D[31:16]=bf16(S1), RNE on gfx950.
static __device__ __forceinline__ unsigned cvt_pk_bf16(float lo, float hi) {
    unsigned r;
    asm("v_cvt_pk_bf16_f32 %0, %1, %2" : "=v"(r) : "v"(lo), "v"(hi));
    return r;
}
static __device__ __forceinline__ float fexp2(float x) { return __builtin_amdgcn_exp2f(x); }
static __device__ __forceinline__ float frcp (float x) { return __builtin_amdgcn_rcpf(x); }
static __device__ __forceinline__ float sigmoid_(float x) { return frcp(1.f + fexp2(-1.44269504f * x)); }
static __device__ __forceinline__ float tanh_(float x)    { return 1.f - 2.f * frcp(fexp2(2.88539008f * x) + 1.f); }
// mish(x) = x * tanh(softplus(x)) = x * (1 - 2/((1+e^x)^2 + 1))   [log-free identity]
static __device__ __forceinline__ float mish_f(float x) {
    float ex = fexp2(1.44269504f * x);
    float t1 = 1.f + ex;
    return x * (1.f - 2.f * frcp(t1 * t1 + 1.f));
}

// Fused barrier: drains LDS (cross-wave visibility of ds_writes) but leaves
// vmcnt outstanding -> xf prefetch stays in flight across the barrier (T4).
static __device__ __forceinline__ void bar_lgkm() {
    asm volatile("s_waitcnt lgkmcnt(0)\n\ts_barrier" ::: "memory");
}

#define MFMA16(a, b, c) __builtin_amdgcn_mfma_f32_16x16x32_bf16((a), (b), (c), 0, 0, 0)

// ---------------------------------------------------------------------------
// Hidden-unit storage permutation: storage position p = 32w + 2c + i holds
// original unit U(p) = (2w+i)*16 + c  (paired b32 h/mish LDS traffic).
// W_hh / W_out rows permuted accordingly in prep; W_ih / W_in / biases use
// original unit ids.  Fragment element: lane = q*16 + c16 holds
// k = kt*32 + q*8 + jj.  prep is DEST-LINEAR: thread idx = dest offset,
// inverse-mapped to source.  Row perm within 32-block:
// ks5 = ((k&15)<<1)|((k>>4)&1); inverse k5 = ((s5&1)<<4)|(s5>>1).
// ---------------------------------------------------------------------------
__global__ void prep_kernel(const float* __restrict__ W_in, const float* __restrict__ b_in,
                            const float* __restrict__ W_ih, const float* __restrict__ b_ih,
                            const float* __restrict__ W_hh, const float* __restrict__ W_out,
                            unsigned short* __restrict__ wsWhh, unsigned short* __restrict__ wsWih,
                            unsigned short* __restrict__ wsWin, unsigned short* __restrict__ wsWo,
                            float* __restrict__ wsBx) {
    int idx = blockIdx.x * 256 + threadIdx.x;
    if (idx < 196608) {                       // W_hh 256x768 (rows permuted)
        int f = idx >> 9, rem = idx & 511, l = rem >> 3, jj = rem & 7;
        int q = l >> 4, c16 = l & 15;
        int g = f % 3, f2 = f / 3, i = f2 & 1, f3 = f2 >> 1;   // f3 = w*8+kt
        int kt = f3 & 7, w = f3 >> 3;
        int s5 = q * 8 + jj;
        int k = kt * 32 + ((s5 & 1) << 4) + (s5 >> 1);
        int n = g * 256 + (2 * w + i) * 16 + c16;
        wsWhh[idx] = f2bf(W_hh[k * NGATE + n]);
    } else if (idx < 245760) {                // W_ih 64x768 (x rows: no perm)
        int d = idx - 196608;
        int f = d >> 9, rem = d & 511, l = rem >> 3, jj = rem & 7;
        int q = l >> 4, c16 = l & 15;
        int g = f % 3, f2 = f / 3, i = f2 & 1, f3 = f2 >> 1;   // f3 = w*2+kt
        int kt = f3 & 1, w = f3 >> 1;
        int k = kt * 32 + q * 8 + jj;
        int n = g * 256 + (2 * w + i) * 16 + c16;
        wsWih[d] = f2bf(W_ih[k * NGATE + n]);
    } else if (idx < 253952) {                // W_in 128x64 (no perm)
        int d = idx - 245760;
        int f = d >> 9, rem = d & 511, l = rem >> 3, jj = rem & 7;
        int q = l >> 4, nl = l & 15;
        int nt = f & 3, kt = f >> 2;
        int k = kt * 32 + q * 8 + jj;
        int n = nt * 16 + nl;
        wsWin[d] = f2bf(W_in[k * PROJJ + n]);
    } else if (idx < 262144) {                // W_out 256x32 (rows permuted)
        int d = idx - 253952;
        int f = d >> 9, rem = d & 511, l = rem >> 3, jj = rem & 7;
        int q = l >> 4, nl = l & 15;
        int kt = f & 7, nt = f >> 3;
        int s5 = q * 8 + jj;
        int k = kt * 32 + ((s5 & 1) << 4) + (s5 >> 1);
        int n = nt * 16 + nl;
        wsWo[d] = f2bf((n < LATT) ? W_out[k * LATT + n] : 0.f);
    } else if (idx < 262912) {                // b_x = b_in @ W_ih + b_ih
        int n = idx - 262144;
        float s = b_ih[n];
        for (int j = 0; j < PROJJ; ++j) s += b_in[j] * W_ih[j * NGATE + n];
        wsBx[n] = s;
    }
}

// ---------------------------------------------------------------------------
// x-projection pre-pass v2 (coalesced): block = (group g, 8-timestep chunk).
// Phase 1: stage obs tile [16b x 8t x 128d] global->LDS as bf16; thread map
//   (tl = tid>>5, f4 = tid&31) x 16 batch passes -> each pass reads 4 KB
//   CONTIGUOUS (8 t-rows of one batch).  LDS layout ldsO[tl][bl][136] (pad ->
//   16B-aligned rows; bl-major reads ~2-way banks).
// Phase 2: per wave, 2 timesteps: A-frags from ldsO, B from sWin (LDS),
//   16 MFMA; C scattered via sXP (wave-local) into per-lane A-frag layout:
//   xf[(g*256+t)*1024 + lane*16 + kt*8 + jj] = bf16(x[b=g*16+c16][k])
// R3 BUG (NaN): sWin staging copied only 512 of 1024 uint4 (loop sized for a
// 512-thread block, but this kernel is 256 threads) -> kt>=2 B-frags read
// uninitialized LDS.  Fixed: 4 iterations.
// ---------------------------------------------------------------------------
__global__ __launch_bounds__(256)
void xproj_kernel(const float* __restrict__ obs, const unsigned short* __restrict__ wsWin,
                  unsigned short* __restrict__ xf) {
    __shared__ __align__(16) unsigned short ldsO[8 * 16 * 136];   // 34 KB
    __shared__ __align__(16) unsigned short sWin[8192];           // 16 KB
    __shared__ __align__(16) unsigned short sXP[4][1040];
    const int tid = threadIdx.x, w = tid >> 6, lane = tid & 63, q = lane >> 4, c16 = lane & 15;
    const int bid = blockIdx.x;
    const int g = bid >> 5, tc = bid & 31;
    const int t0x = tc * 8, b0x = g * 16;

    // stage W_in' (16 KB = 1024 uint4) into LDS: 4 iters x 256 threads
    {
        const uint4* s = (const uint4*)wsWin; uint4* d = (uint4*)sWin;
#pragma unroll
        for (int r = 0; r < 4; ++r) d[r * 256 + tid] = s[r * 256 + tid];
    }
    // stage obs tile, coalesced
    {
        const int tl = tid >> 5, f4 = tid & 31;
        const float* base = obs + ((size_t)b0x * TTIME + t0x + tl) * OBS_DIMM + f4 * 4;
#pragma unroll
        for (int p = 0; p < 16; ++p) {
            float4 v = *(const float4*)(base + (size_t)p * TTIME * OBS_DIMM);
            unsigned lo = cvt_pk_bf16(v.x, v.y);
            unsigned hi = cvt_pk_bf16(v.z, v.w);
            *(uint2*)(ldsO + (tl * 16 + p) * 136 + f4 * 4) = make_uint2(lo, hi);
        }
    }
    __syncthreads();

    // per-wave: 2 timesteps
    for (int s = 0; s < 2; ++s) {
        const int tl = w * 2 + s;
        f32x4 acc[4];
#pragma unroll
        for (int nt = 0; nt < 4; ++nt) acc[nt] = (f32x4){0.f, 0.f, 0.f, 0.f};
#pragma unroll
        for (int kt = 0; kt < 4; ++kt) {
            bf16x8 a = *(const bf16x8*)(ldsO + (tl * 16 + c16) * 136 + kt * 32 + q * 8);
#pragma unroll
            for (int nt = 0; nt < 4; ++nt)
                acc[nt] = MFMA16(a, *(const bf16x8*)(sWin + (kt * 4 + nt) * 512 + lane * 8), acc[nt]);
        }
        // scatter C (row=q*4+r=batch, col=nt*16+c16=unit) into A-frag layout
#pragma unroll
        for (int nt = 0; nt < 4; ++nt) {
            int unit = nt * 16 + c16;
            int ktp = unit >> 5, qp = (unit >> 3) & 3, jjp = unit & 7;
#pragma unroll
            for (int r = 0; r < 4; ++r)
                sXP[w][(qp * 16 + q * 4 + r) * 16 + ktp * 8 + jjp] = f2bf(acc[nt][r]);
        }
        // wave-local: per-wave LDS ops execute in order; same-address rw safe
        unsigned short* dst = xf + (size_t)(g * 256 + t0x + tl) * 1024 + lane * 16;
        *(bf16x8*)dst       = *(const bf16x8*)(sXP[w] + lane * 16);
        *(bf16x8*)(dst + 8) = *(const bf16x8*)(sXP[w] + lane * 16 + 8);
    }
}

// ---------------------------------------------------------------------------
// Persistent-weight GRU, ONE barrier per step.
// grid = 64 batch-groups x 4 time-chunks = 256 blocks x 512 thr.
// W_hh in regs (48 frags); W_ih/W_out in LDS; x pre-projected; gate biases
// in 8 persistent VGPRs (no per-step sBias reads).
// ---------------------------------------------------------------------------
__global__ __launch_bounds__(512, 2)
void gru_kernel(const int* __restrict__ is_init, const float* __restrict__ hx,
                const float* __restrict__ b_hh, const float* __restrict__ b_out,
                const unsigned short* __restrict__ wsWhh, const unsigned short* __restrict__ wsWih,
                const unsigned short* __restrict__ wsWo, const float* __restrict__ wsBx,
                const unsigned short* __restrict__ xf,
                float* __restrict__ out, float* __restrict__ hfin) {
    __shared__ __align__(16) unsigned short sWih[49152];          // 96 KB
    __shared__ __align__(16) unsigned short sWo[8192];            // 16 KB
    __shared__ __align__(16) unsigned short sH[2][MBLK * HSTR];   // h double buffer
    __shared__ __align__(16) unsigned short sM[3][MBLK * HSTR];   // mish triple buffer
    __shared__ __align__(16) float sBias[1056];                   // gates + out bias
    __shared__ unsigned sInit[MBLK][8];                           // is_init bitmask
    __shared__ int sT;

    const int tid  = threadIdx.x;
    const int w    = tid >> 6;
    const int lane = tid & 63;
    const int q    = lane >> 4;
    const int c16  = lane & 15;
    const int bid  = blockIdx.x;
    const int g    = bid & (NGROUP - 1);
    const int ch   = bid >> 6;
    const int b0   = g * MBLK;
    const int t0   = ch * CHUNK;
    const int tend = t0 + CHUNK;

    // ---- persistent W_hh fragments: 48 x bf16x8 = 192 regs, loaded once ----
    const unsigned short* whh_p = wsWhh + (size_t)w * 24576 + lane * 8;
    bf16x8 Whh[48];
#pragma unroll
    for (int f = 0; f < 48; ++f)
        Whh[f] = *(const bf16x8*)(whh_p + (size_t)f * 512);

    // ---- stage W_ih' / W_out' into LDS (512 thr x 16B per iter) ----
    {
        const uint4* s1 = (const uint4*)wsWih; uint4* d1 = (uint4*)sWih;
#pragma unroll
        for (int r = 0; r < 12; ++r) d1[r * 512 + tid] = s1[r * 512 + tid];
        const uint4* s3 = (const uint4*)wsWo;  uint4* d3 = (uint4*)sWo;
#pragma unroll
        for (int r = 0; r < 2; ++r) d3[r * 512 + tid] = s3[r * 512 + tid];
    }
    // ---- biases to LDS ----
    if (tid < 256) {
        sBias[tid]       = wsBx[tid] + b_hh[tid];
        sBias[256 + tid] = wsBx[HIDD + tid] + b_hh[HIDD + tid];
        sBias[512 + tid] = wsBx[2 * HIDD + tid];
        sBias[768 + tid] = b_hh[2 * HIDD + tid];
    } else if (tid < 288) {
        int col = tid - 256;
        sBias[1024 + col] = (col < LATT) ? b_out[col] : 0.f;
    }
    // ---- is_init bitmask: bit t of batch b ----
    if (tid < 128) {
        int b = tid >> 3, wd = tid & 7;
        unsigned m = 0;
        const int* ip = is_init + (size_t)(b0 + b) * TTIME + wd * 32;
#pragma unroll
        for (int j = 0; j < 32; ++j) m |= (ip[j] != 0 ? 1u : 0u) << j;
        sInit[b][wd] = m;
    }
    if (tid == 0) sT = (ch == 0) ? 0 : 0x7fffffff;
    __syncthreads();

    // ---- gate biases -> persistent VGPRs (col u = (2w+i)*16 + c16) ----
    const int u0 = 2 * w * 16 + c16, u1 = (2 * w + 1) * 16 + c16;
    const float bR0 = sBias[u0],       bR1 = sBias[u1];
    const float bZ0 = sBias[256 + u0], bZ1 = sBias[256 + u1];
    const float bX0 = sBias[512 + u0], bX1 = sBias[512 + u1];
    const float bH0 = sBias[768 + u0], bH1 = sBias[768 + u1];

    // ---- start time: most recent reset in [1, t0), min over group ----
    if (ch > 0 && tid < MBLK) {
        int fs = 0;
        for (int wi = (t0 >> 5) - 1; wi >= 0; --wi) {
            unsigned m = sInit[tid][wi];
            if (wi == 0) m &= ~1u;
            if (m) { fs = wi * 32 + 31 - __builtin_clz(m); break; }
        }
        atomicMin(&sT, fs);
    }
    __syncthreads();
    const int tstart = sT;

    // ---- init h (hx if tstart==0 && !reset, else 0); own pairs in regs ----
    unsigned hReg[4];
#pragma unroll
    for (int r = 0; r < 4; ++r) {
        int b = q * 4 + r;
        unsigned rbit = (sInit[b][tstart >> 5] >> (tstart & 31)) & 1u;
        float h0v = 0.f, h1v = 0.f;
        if (tstart == 0 && !rbit) {
            const float* hp = hx + (size_t)(b0 + b) * HIDD;
            h0v = hp[2 * w * 16 + c16];
            h1v = hp[(2 * w + 1) * 16 + c16];
        }
        unsigned pk = (unsigned)f2bf(h0v) | ((unsigned)f2bf(h1v) << 16);
        hReg[r] = pk;
        ((unsigned*)sH[0])[b * 132 + w * 16 + c16] = pk;
    }
    // ---- prime x fragments for tstart ----
    bf16x8 X0, X1;
    {
        const unsigned short* xp = xf + (size_t)(g * 256 + tstart) * 1024 + lane * 16;
        X0 = *(const bf16x8*)xp; X1 = *(const bf16x8*)(xp + 8);
    }
    const unsigned short* wihp = sWih + w * 6144 + lane * 8;
    unsigned short* sHr = sH[0];
    unsigned short* sHw = sH[1];
    unsigned short* pWm = sM[tstart % 3];
    unsigned short* pR1 = sM[(tstart + 2) % 3];   // (t-1)%3
    unsigned short* pR2 = sM[(tstart + 1) % 3];   // (t-2)%3
    __syncthreads();

    f32x4 accR[2], accZ[2], accXN[2], accHN[2];
    auto accfill = [&]() {                        // bias + x-part (12 MFMA)
        accR[0]  = (f32x4){bR0, bR0, bR0, bR0};
        accZ[0]  = (f32x4){bZ0, bZ0, bZ0, bZ0};
        accXN[0] = (f32x4){bX0, bX0, bX0, bX0};
        accHN[0] = (f32x4){bH0, bH0, bH0, bH0};
        accR[1]  = (f32x4){bR1, bR1, bR1, bR1};
        accZ[1]  = (f32x4){bZ1, bZ1, bZ1, bZ1};
        accXN[1] = (f32x4){bX1, bX1, bX1, bX1};
        accHN[1] = (f32x4){bH1, bH1, bH1, bH1};
#pragma unroll
        for (int i = 0; i < 2; ++i) {
            accR[i]  = MFMA16(X0, *(const bf16x8*)(wihp + (i * 3 + 0) * 512), accR[i]);
            accZ[i]  = MFMA16(X0, *(const bf16x8*)(wihp + (i * 3 + 1) * 512), accZ[i]);
            accXN[i] = MFMA16(X0, *(const bf16x8*)(wihp + (i * 3 + 2) * 512), accXN[i]);
            accR[i]  = MFMA16(X1, *(const bf16x8*)(wihp + (6 + i * 3 + 0) * 512), accR[i]);
            accZ[i]  = MFMA16(X1, *(const bf16x8*)(wihp + (6 + i * 3 + 1) * 512), accZ[i]);
            accXN[i] = MFMA16(X1, *(const bf16x8*)(wihp + (6 + i * 3 + 2) * 512), accXN[i]);
        }
    };
    accfill();                                    // for tstart

    for (int t = tstart; t < tend; ++t) {
        // ---- prefetch x(t+1): stays in flight across the fused barrier ----
        {
            int tn = (t + 1 < TTIME) ? t + 1 : TTIME - 1;
            const unsigned short* xp = xf + (size_t)(g * 256 + tn) * 1024 + lane * 16;
            X0 = *(const bf16x8*)xp; X1 = *(const bf16x8*)(xp + 8);
        }
        // ---- h-part: A from sH (LDS), B from registers (48 MFMA) ----
#pragma unroll
        for (int kt = 0; kt < 8; ++kt) {
            bf16x8 a = *(const bf16x8*)(sHr + c16 * HSTR + kt * 32 + q * 8);
#pragma unroll
            for (int i = 0; i < 2; ++i) {
                accR[i]  = MFMA16(a, Whh[kt * 6 + i * 3 + 0], accR[i]);
                accZ[i]  = MFMA16(a, Whh[kt * 6 + i * 3 + 1], accZ[i]);
                accHN[i] = MFMA16(a, Whh[kt * 6 + i * 3 + 2], accHN[i]);
            }
        }
        // ---- out-proj tb = t-2 on rotating wave pair ----
        f32x4 oa;
        const bool doO = (t >= t0 + 2) && ((w >> 1) == (t & 3));
        if (doO) {
            int nt = w & 1;
            float bo = sBias[1024 + nt * 16 + c16];
            oa = (f32x4){bo, bo, bo, bo};
            const unsigned short* smp = pR2 + c16 * HSTR + q * 8;
#pragma unroll
            for (int kt = 0; kt < 8; ++kt)
                oa = MFMA16(*(const bf16x8*)(smp + kt * 32),
                            *(const bf16x8*)(sWo + (nt * 8 + kt) * 512 + lane * 8), oa);
        }
        // ---- reset mask for t+1 from bitmask (broadcast LDS reads) ----
        int m4 = 0;
        if (t + 1 < tend) {
            int wd = (t + 1) >> 5, bt = (t + 1) & 31;
#pragma unroll
            for (int r = 0; r < 4; ++r)
                m4 |= (int)((sInit[q * 4 + r][wd] >> bt) & 1u) << r;
        }
        // ---- U: gates + h update (hOld from registers) ----
        const bool emit = (t >= t0);
#pragma unroll
        for (int r = 0; r < 4; ++r) {
            int bl = q * 4 + r;
            float hs0 = bf2f((unsigned short)(hReg[r] & 0xffffu));
            float hs1 = bf2f((unsigned short)(hReg[r] >> 16));
            float rr0 = sigmoid_(accR[0][r]), rr1 = sigmoid_(accR[1][r]);
            float zz0 = sigmoid_(accZ[0][r]), zz1 = sigmoid_(accZ[1][r]);
            float nn0 = tanh_(accXN[0][r] + rr0 * accHN[0][r]);
            float nn1 = tanh_(accXN[1][r] + rr1 * accHN[1][r]);
            float h0 = (1.f - zz0) * nn0 + zz0 * hs0;
            float h1 = (1.f - zz1) * nn1 + zz1 * hs1;
            if (emit)
                ((unsigned*)pWm)[bl * 132 + w * 16 + c16] =
                    cvt_pk_bf16(mish_f(h0), mish_f(h1));
            if ((m4 >> r) & 1) { h0 = 0.f; h1 = 0.f; }   // episode reset for t+1
            unsigned pk = cvt_pk_bf16(h0, h1);
            hReg[r] = pk;
            ((unsigned*)sHw)[bl * 132 + w * 16 + c16] = pk;
        }
        // ---- out stores (pair waves; un-waited, drains lazily) ----
        if (doO) {
            int nt = w & 1, col = nt * 16 + c16, tb = t - 2;
            if (col < LATT) {
#pragma unroll
                for (int r = 0; r < 4; ++r)
                    out[((size_t)(b0 + q * 4 + r) * TTIME + tb) * LATT + col] = oa[r];
            }
        }
        // ---- next-step bias + x-part (12 MFMA, consumes prefetched X) ----
        if (t + 1 < tend) accfill();
        bar_lgkm();
        { unsigned short* tp = sHr; sHr = sHw; sHw = tp; }
        { unsigned short* tp = pWm; pWm = pR2; pR2 = pR1; pR1 = tp; }
    }

    // ---- epilogue out-proj: tend-2 (waves 0,1) and tend-1 (waves 2,3) ----
    if (w < 4) {
        int nt = w & 1;
        unsigned short* pR = (w < 2) ? pR2 : pR1;
        int tb = (w < 2) ? tend - 2 : tend - 1;
        float bo = sBias[1024 + nt * 16 + c16];
        f32x4 oa2 = (f32x4){bo, bo, bo, bo};
        const unsigned short* smp = pR + c16 * HSTR + q * 8;
#pragma unroll
        for (int kt = 0; kt < 8; ++kt)
            oa2 = MFMA16(*(const bf16x8*)(smp + kt * 32),
                         *(const bf16x8*)(sWo + (nt * 8 + kt) * 512 + lane * 8), oa2);
        int col = nt * 16 + c16;
        if (col < LATT) {
#pragma unroll
            for (int r = 0; r < 4; ++r)
                out[((size_t)(b0 + q * 4 + r) * TTIME + tb) * LATT + col] = oa2[r];
        }
    }
    // ---- h_final straight from registers (each thread owns its pairs) ----
    if (ch == NCHUNK - 1) {
#pragma unroll
        for (int r = 0; r < 4; ++r) {
            float* hp = hfin + (size_t)(b0 + q * 4 + r) * HIDD;
            hp[2 * w * 16 + c16]       = bf2f((unsigned short)(hReg[r] & 0xffffu));
            hp[(2 * w + 1) * 16 + c16] = bf2f((unsigned short)(hReg[r] >> 16));
        }
    }
}

extern "C" void kernel_launch(void* const* d_in, const int* in_sizes, int n_in,
                              void* d_out, int out_size, void* d_ws, size_t ws_size,
                              hipStream_t stream) {
    const float* obs    = (const float*)d_in[0];
    const int*   isini  = (const int*)d_in[1];
    const float* hx     = (const float*)d_in[2];
    const float* W_in   = (const float*)d_in[3];
    const float* b_in   = (const float*)d_in[4];
    const float* W_ih   = (const float*)d_in[5];
    const float* b_ih   = (const float*)d_in[6];
    const float* W_hh   = (const float*)d_in[7];
    const float* b_hh   = (const float*)d_in[8];
    const float* W_out  = (const float*)d_in[9];
    const float* b_out  = (const float*)d_in[10];

    // workspace: xf (pre-projected x, bf16, fragment layout) | Whh' | Wih' |
    // Win' | Wo' | b_x   (~34.1 MB total)
    unsigned short* xfbuf = (unsigned short*)d_ws;              // 16777216 ushorts
    unsigned short* wsWhh = xfbuf + (size_t)BBATCH * TTIME * 64;
    unsigned short* wsWih = wsWhh + 196608;
    unsigned short* wsWin = wsWih + 49152;
    unsigned short* wsWo  = wsWin + 8192;
    float*          wsBx  = (float*)(wsWo + 8192);

    float* outp = (float*)d_out;
    float* hfin = outp + (size_t)BBATCH * TTIME * LATT;

    prep_kernel<<<1027, 256, 0, stream>>>(W_in, b_in, W_ih, b_ih, W_hh, W_out,
                                          wsWhh, wsWih, wsWin, wsWo, wsBx);
    xproj_kernel<<<2048, 256, 0, stream>>>(obs, wsWin, xfbuf);
    gru_kernel<<<256, 512, 0, stream>>>(isini, hx, b_hh, b_out,
                                        wsWhh, wsWih, wsWo, wsBx, xfbuf, outp, hfin);
}

// Round 5
// 478.901 us; speedup vs baseline: 1.3104x; 1.3104x over previous
//
#include <hip/hip_runtime.h>
#include <cstdint>
#include <cstddef>

// Problem constants
#define OBS_DIMM 128
#define PROJJ    64
#define HIDD     256
#define LATT     24
#define BBATCH   1024
#define TTIME    256
#define NGATE    768   // 3*HID
#define MBLK     16    // batches per block
#define CHUNK    64    // timesteps per block
#define NGROUP   64
#define NCHUNK   4
#define HSTR     264   // h/mish row stride (ushorts): 256 + 8 pad (16B-aligned, bank-skewed)

using bf16x8 = __attribute__((ext_vector_type(8))) short;   // 8 bf16 in 4 VGPRs
using f32x4  = __attribute__((ext_vector_type(4))) float;

static __device__ __forceinline__ unsigned short f2bf(float f) {
    unsigned u = __builtin_bit_cast(unsigned, f);
    u += 0x7fffu + ((u >> 16) & 1u);          // RNE
    return (unsigned short)(u >> 16);
}
static __device__ __forceinline__ float bf2f(unsigned short h) {
    return __builtin_bit_cast(float, ((unsigned)h) << 16);
}
// Packed RNE f32->bf16 pair: 1 instr, bit-identical to f2bf (absmax canary).
static __device__ __forceinline__ unsigned cvt_pk_bf16(float lo, float hi) {
    unsigned r;
    asm("v_cvt_pk_bf16_f32 %0, %1, %2" : "=v"(r) : "v"(lo), "v"(hi));
    return r;
}
static __device__ __forceinline__ float fexp2(float x) { return __builtin_amdgcn_exp2f(x); }
static __device__ __forceinline__ float frcp (float x) { return __builtin_amdgcn_rcpf(x); }
static __device__ __forceinline__ float sigmoid_(float x) { return frcp(1.f + fexp2(-1.44269504f * x)); }
static __device__ __forceinline__ float tanh_(float x)    { return 1.f - 2.f * frcp(fexp2(2.88539008f * x) + 1.f); }
// mish(x) = x * tanh(softplus(x)) = x * (1 - 2/((1+e^x)^2 + 1))   [log-free identity]
static __device__ __forceinline__ float mish_f(float x) {
    float ex = fexp2(1.44269504f * x);
    float t1 = 1.f + ex;
    return x * (1.f - 2.f * frcp(t1 * t1 + 1.f));
}

// Fused barrier: drains LDS (cross-wave visibility of ds_writes) but leaves
// vmcnt outstanding -> xf prefetch stays in flight across the barrier (T4).
static __device__ __forceinline__ void bar_lgkm() {
    asm volatile("s_waitcnt lgkmcnt(0)\n\ts_barrier" ::: "memory");
}

#define MFMA16(a, b, c) __builtin_amdgcn_mfma_f32_16x16x32_bf16((a), (b), (c), 0, 0, 0)

// ---------------------------------------------------------------------------
// Hidden-unit storage permutation: storage position p = 32w + 2c + i holds
// original unit U(p) = (2w+i)*16 + c  (paired b32 h/mish LDS traffic).
// W_hh / W_out rows permuted accordingly in prep; W_ih / W_in / biases use
// original unit ids.  Fragment element: lane = q*16 + c16 holds
// k = kt*32 + q*8 + jj.  prep is DEST-LINEAR: thread idx = dest offset,
// inverse-mapped to source.  Row perm within 32-block:
// ks5 = ((k&15)<<1)|((k>>4)&1); inverse k5 = ((s5&1)<<4)|(s5>>1).
// ---------------------------------------------------------------------------
__global__ void prep_kernel(const float* __restrict__ W_in, const float* __restrict__ b_in,
                            const float* __restrict__ W_ih, const float* __restrict__ b_ih,
                            const float* __restrict__ W_hh, const float* __restrict__ W_out,
                            unsigned short* __restrict__ wsWhh, unsigned short* __restrict__ wsWih,
                            unsigned short* __restrict__ wsWin, unsigned short* __restrict__ wsWo,
                            float* __restrict__ wsBx) {
    int idx = blockIdx.x * 256 + threadIdx.x;
    if (idx < 196608) {                       // W_hh 256x768 (rows permuted)
        int f = idx >> 9, rem = idx & 511, l = rem >> 3, jj = rem & 7;
        int q = l >> 4, c16 = l & 15;
        int g = f % 3, f2 = f / 3, i = f2 & 1, f3 = f2 >> 1;   // f3 = w*8+kt
        int kt = f3 & 7, w = f3 >> 3;
        int s5 = q * 8 + jj;
        int k = kt * 32 + ((s5 & 1) << 4) + (s5 >> 1);
        int n = g * 256 + (2 * w + i) * 16 + c16;
        wsWhh[idx] = f2bf(W_hh[k * NGATE + n]);
    } else if (idx < 245760) {                // W_ih 64x768 (x rows: no perm)
        int d = idx - 196608;
        int f = d >> 9, rem = d & 511, l = rem >> 3, jj = rem & 7;
        int q = l >> 4, c16 = l & 15;
        int g = f % 3, f2 = f / 3, i = f2 & 1, f3 = f2 >> 1;   // f3 = w*2+kt
        int kt = f3 & 1, w = f3 >> 1;
        int k = kt * 32 + q * 8 + jj;
        int n = g * 256 + (2 * w + i) * 16 + c16;
        wsWih[d] = f2bf(W_ih[k * NGATE + n]);
    } else if (idx < 253952) {                // W_in 128x64 (no perm)
        int d = idx - 245760;
        int f = d >> 9, rem = d & 511, l = rem >> 3, jj = rem & 7;
        int q = l >> 4, nl = l & 15;
        int nt = f & 3, kt = f >> 2;
        int k = kt * 32 + q * 8 + jj;
        int n = nt * 16 + nl;
        wsWin[d] = f2bf(W_in[k * PROJJ + n]);
    } else if (idx < 262144) {                // W_out 256x32 (rows permuted)
        int d = idx - 253952;
        int f = d >> 9, rem = d & 511, l = rem >> 3, jj = rem & 7;
        int q = l >> 4, nl = l & 15;
        int kt = f & 7, nt = f >> 3;
        int s5 = q * 8 + jj;
        int k = kt * 32 + ((s5 & 1) << 4) + (s5 >> 1);
        int n = nt * 16 + nl;
        wsWo[d] = f2bf((n < LATT) ? W_out[k * LATT + n] : 0.f);
    } else if (idx < 262912) {                // b_x = b_in @ W_ih + b_ih
        int n = idx - 262144;
        float s = b_ih[n];
        for (int j = 0; j < PROJJ; ++j) s += b_in[j] * W_ih[j * NGATE + n];
        wsBx[n] = s;
    }
}

// ---------------------------------------------------------------------------
// x-projection pre-pass v2 (coalesced): block = (group g, 8-timestep chunk).
// Phase 1: stage obs tile [16b x 8t x 128d] global->LDS as bf16 (each pass
//   reads 4 KB contiguous).  Phase 2: per wave, 2 timesteps: A from ldsO,
//   B from sWin, 16 MFMA; C scattered via sXP into per-lane A-frag layout:
//   xf[(g*256+t)*1024 + lane*16 + kt*8 + jj] = bf16(x[b=g*16+c16][k])
// ---------------------------------------------------------------------------
__global__ __launch_bounds__(256)
void xproj_kernel(const float* __restrict__ obs, const unsigned short* __restrict__ wsWin,
                  unsigned short* __restrict__ xf) {
    __shared__ __align__(16) unsigned short ldsO[8 * 16 * 136];   // 34 KB
    __shared__ __align__(16) unsigned short sWin[8192];           // 16 KB
    __shared__ __align__(16) unsigned short sXP[4][1040];
    const int tid = threadIdx.x, w = tid >> 6, lane = tid & 63, q = lane >> 4, c16 = lane & 15;
    const int bid = blockIdx.x;
    const int g = bid >> 5, tc = bid & 31;
    const int t0x = tc * 8, b0x = g * 16;

    // stage W_in' (16 KB = 1024 uint4) into LDS: 4 iters x 256 threads
    {
        const uint4* s = (const uint4*)wsWin; uint4* d = (uint4*)sWin;
#pragma unroll
        for (int r = 0; r < 4; ++r) d[r * 256 + tid] = s[r * 256 + tid];
    }
    // stage obs tile, coalesced
    {
        const int tl = tid >> 5, f4 = tid & 31;
        const float* base = obs + ((size_t)b0x * TTIME + t0x + tl) * OBS_DIMM + f4 * 4;
#pragma unroll
        for (int p = 0; p < 16; ++p) {
            float4 v = *(const float4*)(base + (size_t)p * TTIME * OBS_DIMM);
            unsigned lo = cvt_pk_bf16(v.x, v.y);
            unsigned hi = cvt_pk_bf16(v.z, v.w);
            *(uint2*)(ldsO + (tl * 16 + p) * 136 + f4 * 4) = make_uint2(lo, hi);
        }
    }
    __syncthreads();

    // per-wave: 2 timesteps
    for (int s = 0; s < 2; ++s) {
        const int tl = w * 2 + s;
        f32x4 acc[4];
#pragma unroll
        for (int nt = 0; nt < 4; ++nt) acc[nt] = (f32x4){0.f, 0.f, 0.f, 0.f};
#pragma unroll
        for (int kt = 0; kt < 4; ++kt) {
            bf16x8 a = *(const bf16x8*)(ldsO + (tl * 16 + c16) * 136 + kt * 32 + q * 8);
#pragma unroll
            for (int nt = 0; nt < 4; ++nt)
                acc[nt] = MFMA16(a, *(const bf16x8*)(sWin + (kt * 4 + nt) * 512 + lane * 8), acc[nt]);
        }
        // scatter C (row=q*4+r=batch, col=nt*16+c16=unit) into A-frag layout
#pragma unroll
        for (int nt = 0; nt < 4; ++nt) {
            int unit = nt * 16 + c16;
            int ktp = unit >> 5, qp = (unit >> 3) & 3, jjp = unit & 7;
#pragma unroll
            for (int r = 0; r < 4; ++r)
                sXP[w][(qp * 16 + q * 4 + r) * 16 + ktp * 8 + jjp] = f2bf(acc[nt][r]);
        }
        // wave-local: per-wave LDS ops execute in order; same-address rw safe
        unsigned short* dst = xf + (size_t)(g * 256 + t0x + tl) * 1024 + lane * 16;
        *(bf16x8*)dst       = *(const bf16x8*)(sXP[w] + lane * 16);
        *(bf16x8*)(dst + 8) = *(const bf16x8*)(sXP[w] + lane * 16 + 8);
    }
}

// ---------------------------------------------------------------------------
// Persistent-weight GRU, ONE barrier per step.
// grid = 64 batch-groups x 4 time-chunks = 256 blocks x 512 thr.
// W_hh in regs (48 frags = 192 acc-regs); W_ih/W_out in LDS; x pre-projected.
// REGISTER BUDGET NOTE (R4 post-mortem): at launch_bounds(512,2) the unified
// budget is 256 regs/wave and this kernel sits at exactly 128 VGPR + 128 AGPR.
// Hoisting even 8 more persistent floats (gate biases) causes scratch spill
// in the hot loop (+60 MB HBM, +136 us).  Gate biases MUST stay in sBias LDS.
// ---------------------------------------------------------------------------
__global__ __launch_bounds__(512, 2)
void gru_kernel(const int* __restrict__ is_init, const float* __restrict__ hx,
                const float* __restrict__ b_hh, const float* __restrict__ b_out,
                const unsigned short* __restrict__ wsWhh, const unsigned short* __restrict__ wsWih,
                const unsigned short* __restrict__ wsWo, const float* __restrict__ wsBx,
                const unsigned short* __restrict__ xf,
                float* __restrict__ out, float* __restrict__ hfin) {
    __shared__ __align__(16) unsigned short sWih[49152];          // 96 KB
    __shared__ __align__(16) unsigned short sWo[8192];            // 16 KB
    __shared__ __align__(16) unsigned short sH[2][MBLK * HSTR];   // h double buffer
    __shared__ __align__(16) unsigned short sM[3][MBLK * HSTR];   // mish triple buffer
    __shared__ __align__(16) float sBias[1056];                   // gates + out bias
    __shared__ unsigned sInit[MBLK][8];                           // is_init bitmask
    __shared__ int sT;

    const int tid  = threadIdx.x;
    const int w    = tid >> 6;
    const int lane = tid & 63;
    const int q    = lane >> 4;
    const int c16  = lane & 15;
    const int bid  = blockIdx.x;
    const int g    = bid & (NGROUP - 1);
    const int ch   = bid >> 6;
    const int b0   = g * MBLK;
    const int t0   = ch * CHUNK;
    const int tend = t0 + CHUNK;

    // ---- persistent W_hh fragments: 48 x bf16x8 = 192 regs, loaded once ----
    const unsigned short* whh_p = wsWhh + (size_t)w * 24576 + lane * 8;
    bf16x8 Whh[48];
#pragma unroll
    for (int f = 0; f < 48; ++f)
        Whh[f] = *(const bf16x8*)(whh_p + (size_t)f * 512);

    // ---- stage W_ih' / W_out' into LDS (512 thr x 16B per iter) ----
    {
        const uint4* s1 = (const uint4*)wsWih; uint4* d1 = (uint4*)sWih;
#pragma unroll
        for (int r = 0; r < 12; ++r) d1[r * 512 + tid] = s1[r * 512 + tid];
        const uint4* s3 = (const uint4*)wsWo;  uint4* d3 = (uint4*)sWo;
#pragma unroll
        for (int r = 0; r < 2; ++r) d3[r * 512 + tid] = s3[r * 512 + tid];
    }
    // ---- biases to LDS ----
    if (tid < 256) {
        sBias[tid]       = wsBx[tid] + b_hh[tid];
        sBias[256 + tid] = wsBx[HIDD + tid] + b_hh[HIDD + tid];
        sBias[512 + tid] = wsBx[2 * HIDD + tid];
        sBias[768 + tid] = b_hh[2 * HIDD + tid];
    } else if (tid < 288) {
        int col = tid - 256;
        sBias[1024 + col] = (col < LATT) ? b_out[col] : 0.f;
    }
    // ---- is_init bitmask: bit t of batch b ----
    if (tid < 128) {
        int b = tid >> 3, wd = tid & 7;
        unsigned m = 0;
        const int* ip = is_init + (size_t)(b0 + b) * TTIME + wd * 32;
#pragma unroll
        for (int j = 0; j < 32; ++j) m |= (ip[j] != 0 ? 1u : 0u) << j;
        sInit[b][wd] = m;
    }
    if (tid == 0) sT = (ch == 0) ? 0 : 0x7fffffff;
    __syncthreads();

    // ---- start time: most recent reset in [1, t0), min over group ----
    if (ch > 0 && tid < MBLK) {
        int fs = 0;
        for (int wi = (t0 >> 5) - 1; wi >= 0; --wi) {
            unsigned m = sInit[tid][wi];
            if (wi == 0) m &= ~1u;
            if (m) { fs = wi * 32 + 31 - __builtin_clz(m); break; }
        }
        atomicMin(&sT, fs);
    }
    __syncthreads();
    const int tstart = sT;

    // ---- init h (hx if tstart==0 && !reset, else 0); own pairs in regs ----
    unsigned hReg[4];
#pragma unroll
    for (int r = 0; r < 4; ++r) {
        int b = q * 4 + r;
        unsigned rbit = (sInit[b][tstart >> 5] >> (tstart & 31)) & 1u;
        float h0v = 0.f, h1v = 0.f;
        if (tstart == 0 && !rbit) {
            const float* hp = hx + (size_t)(b0 + b) * HIDD;
            h0v = hp[2 * w * 16 + c16];
            h1v = hp[(2 * w + 1) * 16 + c16];
        }
        unsigned pk = (unsigned)f2bf(h0v) | ((unsigned)f2bf(h1v) << 16);
        hReg[r] = pk;
        ((unsigned*)sH[0])[b * 132 + w * 16 + c16] = pk;
    }
    // ---- prime x fragments for tstart ----
    bf16x8 X0, X1;
    {
        const unsigned short* xp = xf + (size_t)(g * 256 + tstart) * 1024 + lane * 16;
        X0 = *(const bf16x8*)xp; X1 = *(const bf16x8*)(xp + 8);
    }
    const unsigned short* wihp = sWih + w * 6144 + lane * 8;
    unsigned short* sHr = sH[0];
    unsigned short* sHw = sH[1];
    unsigned short* pWm = sM[tstart % 3];
    unsigned short* pR1 = sM[(tstart + 2) % 3];   // (t-1)%3
    unsigned short* pR2 = sM[(tstart + 1) % 3];   // (t-2)%3
    __syncthreads();

    f32x4 accR[2], accZ[2], accXN[2], accHN[2];
    auto accfill = [&]() {                        // bias (from LDS!) + x-part (12 MFMA)
#pragma unroll
        for (int i = 0; i < 2; ++i) {
            int u = (2 * w + i) * 16 + c16;
            float vR = sBias[u], vZ = sBias[256 + u], vX = sBias[512 + u], vH = sBias[768 + u];
            accR[i]  = (f32x4){vR, vR, vR, vR};
            accZ[i]  = (f32x4){vZ, vZ, vZ, vZ};
            accXN[i] = (f32x4){vX, vX, vX, vX};
            accHN[i] = (f32x4){vH, vH, vH, vH};
            accR[i]  = MFMA16(X0, *(const bf16x8*)(wihp + (i * 3 + 0) * 512), accR[i]);
            accZ[i]  = MFMA16(X0, *(const bf16x8*)(wihp + (i * 3 + 1) * 512), accZ[i]);
            accXN[i] = MFMA16(X0, *(const bf16x8*)(wihp + (i * 3 + 2) * 512), accXN[i]);
            accR[i]  = MFMA16(X1, *(const bf16x8*)(wihp + (6 + i * 3 + 0) * 512), accR[i]);
            accZ[i]  = MFMA16(X1, *(const bf16x8*)(wihp + (6 + i * 3 + 1) * 512), accZ[i]);
            accXN[i] = MFMA16(X1, *(const bf16x8*)(wihp + (6 + i * 3 + 2) * 512), accXN[i]);
        }
    };
    accfill();                                    // for tstart

    for (int t = tstart; t < tend; ++t) {
        // ---- prefetch x(t+1): stays in flight across the fused barrier ----
        {
            int tn = (t + 1 < TTIME) ? t + 1 : TTIME - 1;
            const unsigned short* xp = xf + (size_t)(g * 256 + tn) * 1024 + lane * 16;
            X0 = *(const bf16x8*)xp; X1 = *(const bf16x8*)(xp + 8);
        }
        // ---- h-part: A from sH (LDS), B from registers (48 MFMA) ----
#pragma unroll
        for (int kt = 0; kt < 8; ++kt) {
            bf16x8 a = *(const bf16x8*)(sHr + c16 * HSTR + kt * 32 + q * 8);
#pragma unroll
            for (int i = 0; i < 2; ++i) {
                accR[i]  = MFMA16(a, Whh[kt * 6 + i * 3 + 0], accR[i]);
                accZ[i]  = MFMA16(a, Whh[kt * 6 + i * 3 + 1], accZ[i]);
                accHN[i] = MFMA16(a, Whh[kt * 6 + i * 3 + 2], accHN[i]);
            }
        }
        // ---- out-proj tb = t-2 on rotating wave pair ----
        f32x4 oa;
        const bool doO = (t >= t0 + 2) && ((w >> 1) == (t & 3));
        if (doO) {
            int nt = w & 1;
            float bo = sBias[1024 + nt * 16 + c16];
            oa = (f32x4){bo, bo, bo, bo};
            const unsigned short* smp = pR2 + c16 * HSTR + q * 8;
#pragma unroll
            for (int kt = 0; kt < 8; ++kt)
                oa = MFMA16(*(const bf16x8*)(smp + kt * 32),
                            *(const bf16x8*)(sWo + (nt * 8 + kt) * 512 + lane * 8), oa);
        }
        // ---- reset mask for t+1 from bitmask (broadcast LDS reads) ----
        int m4 = 0;
        if (t + 1 < tend) {
            int wd = (t + 1) >> 5, bt = (t + 1) & 31;
#pragma unroll
            for (int r = 0; r < 4; ++r)
                m4 |= (int)((sInit[q * 4 + r][wd] >> bt) & 1u) << r;
        }
        // ---- U: gates + h update (hOld from registers) ----
        const bool emit = (t >= t0);
#pragma unroll
        for (int r = 0; r < 4; ++r) {
            int bl = q * 4 + r;
            float hs0 = bf2f((unsigned short)(hReg[r] & 0xffffu));
            float hs1 = bf2f((unsigned short)(hReg[r] >> 16));
            float rr0 = sigmoid_(accR[0][r]), rr1 = sigmoid_(accR[1][r]);
            float zz0 = sigmoid_(accZ[0][r]), zz1 = sigmoid_(accZ[1][r]);
            float nn0 = tanh_(accXN[0][r] + rr0 * accHN[0][r]);
            float nn1 = tanh_(accXN[1][r] + rr1 * accHN[1][r]);
            float h0 = (1.f - zz0) * nn0 + zz0 * hs0;
            float h1 = (1.f - zz1) * nn1 + zz1 * hs1;
            if (emit)
                ((unsigned*)pWm)[bl * 132 + w * 16 + c16] =
                    cvt_pk_bf16(mish_f(h0), mish_f(h1));
            if ((m4 >> r) & 1) { h0 = 0.f; h1 = 0.f; }   // episode reset for t+1
            unsigned pk = cvt_pk_bf16(h0, h1);
            hReg[r] = pk;
            ((unsigned*)sHw)[bl * 132 + w * 16 + c16] = pk;
        }
        // ---- out stores (pair waves; un-waited, drains lazily) ----
        if (doO) {
            int nt = w & 1, col = nt * 16 + c16, tb = t - 2;
            if (col < LATT) {
#pragma unroll
                for (int r = 0; r < 4; ++r)
                    out[((size_t)(b0 + q * 4 + r) * TTIME + tb) * LATT + col] = oa[r];
            }
        }
        // ---- next-step bias + x-part (12 MFMA, consumes prefetched X) ----
        if (t + 1 < tend) accfill();
        bar_lgkm();
        { unsigned short* tp = sHr; sHr = sHw; sHw = tp; }
        { unsigned short* tp = pWm; pWm = pR2; pR2 = pR1; pR1 = tp; }
    }

    // ---- epilogue out-proj: tend-2 (waves 0,1) and tend-1 (waves 2,3) ----
    if (w < 4) {
        int nt = w & 1;
        unsigned short* pR = (w < 2) ? pR2 : pR1;
        int tb = (w < 2) ? tend - 2 : tend - 1;
        float bo = sBias[1024 + nt * 16 + c16];
        f32x4 oa2 = (f32x4){bo, bo, bo, bo};
        const unsigned short* smp = pR + c16 * HSTR + q * 8;
#pragma unroll
        for (int kt = 0; kt < 8; ++kt)
            oa2 = MFMA16(*(const bf16x8*)(smp + kt * 32),
                         *(const bf16x8*)(sWo + (nt * 8 + kt) * 512 + lane * 8), oa2);
        int col = nt * 16 + c16;
        if (col < LATT) {
#pragma unroll
            for (int r = 0; r < 4; ++r)
                out[((size_t)(b0 + q * 4 + r) * TTIME + tb) * LATT + col] = oa2[r];
        }
    }
    // ---- h_final straight from registers (each thread owns its pairs) ----
    if (ch == NCHUNK - 1) {
#pragma unroll
        for (int r = 0; r < 4; ++r) {
            float* hp = hfin + (size_t)(b0 + q * 4 + r) * HIDD;
            hp[2 * w * 16 + c16]       = bf2f((unsigned short)(hReg[r] & 0xffffu));
            hp[(2 * w + 1) * 16 + c16] = bf2f((unsigned short)(hReg[r] >> 16));
        }
    }
}

extern "C" void kernel_launch(void* const* d_in, const int* in_sizes, int n_in,
                              void* d_out, int out_size, void* d_ws, size_t ws_size,
                              hipStream_t stream) {
    const float* obs    = (const float*)d_in[0];
    const int*   isini  = (const int*)d_in[1];
    const float* hx     = (const float*)d_in[2];
    const float* W_in   = (const float*)d_in[3];
    const float* b_in   = (const float*)d_in[4];
    const float* W_ih   = (const float*)d_in[5];
    const float* b_ih   = (const float*)d_in[6];
    const float* W_hh   = (const float*)d_in[7];
    const float* b_hh   = (const float*)d_in[8];
    const float* W_out  = (const float*)d_in[9];
    const float* b_out  = (const float*)d_in[10];

    // workspace: xf (pre-projected x, bf16, fragment layout) | Whh' | Wih' |
    // Win' | Wo' | b_x   (~34.1 MB total)
    unsigned short* xfbuf = (unsigned short*)d_ws;              // 16777216 ushorts
    unsigned short* wsWhh = xfbuf + (size_t)BBATCH * TTIME * 64;
    unsigned short* wsWih = wsWhh + 196608;
    unsigned short* wsWin = wsWih + 49152;
    unsigned short* wsWo  = wsWin + 8192;
    float*          wsBx  = (float*)(wsWo + 8192);

    float* outp = (float*)d_out;
    float* hfin = outp + (size_t)BBATCH * TTIME * LATT;

    prep_kernel<<<1027, 256, 0, stream>>>(W_in, b_in, W_ih, b_ih, W_hh, W_out,
                                          wsWhh, wsWih, wsWin, wsWo, wsBx);
    xproj_kernel<<<2048, 256, 0, stream>>>(obs, wsWin, xfbuf);
    gru_kernel<<<256, 512, 0, stream>>>(isini, hx, b_hh, b_out,
                                        wsWhh, wsWih, wsWo, wsBx, xfbuf, outp, hfin);
}